// Round 1
// baseline (495.295 us; speedup 1.0000x reference)
//
#include <hip/hip_runtime.h>

#define NB 1024
#define N1P 116
#define N2P 200
#define HD 32
#define T1 464   // NB*N1P/256  (118784 rows, exact)
#define T2 800   // NB*N2P/256  (204800 rows, exact)

// ---------------------------------------------------------------------------
// R6: split GEMM1 out of the per-graph kernel.
//  * S = X@Wa is graph-independent (W shared across graphs): one dense GEMM
//    [B*N, N] @ [N,32] per branch. Row counts are exact multiples of 256.
//  * gemm1_kernel: 256-row tiles, thread-per-row (ALL 256 threads active vs
//    NP/256 before), KC=16 double-buffered LDS staging, ONE barrier per chunk
//    (was 2), register prefetch overlaps HBM latency. 40 KB LDS -> 4 blk/CU.
//  * graph_fused: old kernel minus GEMM1 (stage S -> agg1 -> GEMM2 -> agg2 ->
//    pool), branches interleaved by bid&1 for tail balance.
//  * Fallback to the proven R5 monolithic kernel if ws_size too small.
// ---------------------------------------------------------------------------

template <int ST>
__device__ __forceinline__ void agg_phase(int base, int NPv,
                                          const int* __restrict__ cols,
                                          const float* __restrict__ vals,
                                          const float* __restrict__ sup,
                                          float bias, float* __restrict__ outh,
                                          int tid) {
    const int h = tid & 31;
    for (int n = tid >> 5; n < NPv; n += 8) {
        const int4* c4 = (const int4*)(cols + ((size_t)base + n) * 16);
        const float4* v4 = (const float4*)(vals + ((size_t)base + n) * 16);
        float a = bias;
#pragma unroll
        for (int q = 0; q < 4; ++q) {
            const int4 c = c4[q];
            const float4 v = v4[q];
            a += v.x * sup[(c.x - base) * ST + h];
            a += v.y * sup[(c.y - base) * ST + h];
            a += v.z * sup[(c.z - base) * ST + h];
            a += v.w * sup[(c.w - base) * ST + h];
        }
        outh[n * ST + h] = fmaxf(a, 0.f);
    }
}

// ---------------------------------------------------------------------------
// K1: dense GEMM  S[tile*256 + r, :] = X[tile*256 + r, :] @ W   (K x 32)
// ---------------------------------------------------------------------------
template <int K>
__device__ void gemm1_tile(const float* __restrict__ xg,
                           const float* __restrict__ W,
                           float* __restrict__ Sout, float* sX) {
    constexpr int KC = 16;                 // k-chunk
    constexpr int SXS = 20;                // LDS row stride (bank-balanced)
    constexpr int NC = (K + KC - 1) / KC;  // 8 for 116, 13 for 200
    const int tid = threadIdx.x;

    float acc[32];
#pragma unroll
    for (int c = 0; c < 32; ++c) acc[c] = 0.f;

    float4 cur[4];
    auto load_chunk = [&](int kc) {
        const int k0 = kc * KC;
        const int kw = (K - k0) < KC ? (K - k0) : KC;
        const int pieces = kw >> 2;        // tails are multiples of 4 (4, 8)
#pragma unroll
        for (int q = 0; q < 4; ++q) {
            const int i = tid + q * 256;   // i in [0,1024)
            const int row = i >> 2, p = i & 3;
            float4 v = make_float4(0.f, 0.f, 0.f, 0.f);
            if (p < pieces)
                v = *(const float4*)(xg + (size_t)row * K + k0 + p * 4);
            cur[q] = v;
        }
    };

    load_chunk(0);
#pragma unroll 1
    for (int kc = 0; kc < NC; ++kc) {
        float* sb = sX + (kc & 1) * (256 * SXS);
#pragma unroll
        for (int q = 0; q < 4; ++q) {
            const int i = tid + q * 256;
            *(float4*)&sb[(i >> 2) * SXS + (i & 3) * 4] = cur[q];
        }
        __syncthreads();                   // sb ready; prev compute done 2 its ago
        if (kc + 1 < NC) load_chunk(kc + 1);  // prefetch overlaps compute
        const int k0 = kc * KC;
        const int kw = (K - k0) < KC ? (K - k0) : KC;
        const float* xrow = &sb[tid * SXS];
        const float* wb0 = W + (size_t)k0 * 32;
#pragma unroll 1
        for (int k4 = 0; k4 < kw; k4 += 4) {
            const float4 x4 = *(const float4*)&xrow[k4];
#pragma unroll
            for (int kk = 0; kk < 4; ++kk) {
                const float xs = (&x4.x)[kk];
                const float* w = wb0 + (k4 + kk) * 32;   // uniform -> s_load
#pragma unroll
                for (int c4 = 0; c4 < 8; ++c4) {
                    const float4 wv = *(const float4*)&w[c4 * 4];
                    acc[c4 * 4 + 0] += xs * wv.x;
                    acc[c4 * 4 + 1] += xs * wv.y;
                    acc[c4 * 4 + 2] += xs * wv.z;
                    acc[c4 * 4 + 3] += xs * wv.w;
                }
            }
        }
    }

    float* srow = Sout + (size_t)tid * 32;
#pragma unroll
    for (int c4 = 0; c4 < 8; ++c4) {
        float4 o;
        o.x = acc[c4 * 4 + 0]; o.y = acc[c4 * 4 + 1];
        o.z = acc[c4 * 4 + 2]; o.w = acc[c4 * 4 + 3];
        *(float4*)&srow[c4 * 4] = o;
    }
}

__global__ __launch_bounds__(256, 4) void gemm1_kernel(
        const float* __restrict__ x1, const float* __restrict__ W1a,
        float* __restrict__ S1,
        const float* __restrict__ x2, const float* __restrict__ W2a,
        float* __restrict__ S2) {
    __shared__ float sX[2 * 256 * 20];     // 40 KB -> 4 blocks/CU
    const int bid = blockIdx.x;
    if (bid < T1) {
        gemm1_tile<N1P>(x1 + (size_t)bid * 256 * N1P, W1a,
                        S1 + (size_t)bid * 256 * 32, sX);
    } else {
        const int t = bid - T1;
        gemm1_tile<N2P>(x2 + (size_t)t * 256 * N2P, W2a,
                        S2 + (size_t)t * 256 * 32, sX);
    }
}

// ---------------------------------------------------------------------------
// K2: per-graph  stage S -> agg1+relu -> GEMM2 -> agg2+relu -> pool
// ---------------------------------------------------------------------------
template <int NP>
__device__ void graph_phase(int g, const float* __restrict__ S,
                            const int* __restrict__ cols,
                            const float* __restrict__ vals,
                            const float* __restrict__ ba,
                            const float* __restrict__ Wb,
                            const float* __restrict__ bb,
                            float* __restrict__ feats, int foff,
                            float* sSup, float* sH) {
    constexpr int ST = 33;
    const int tid = threadIdx.x;
    const int base = g * NP;
    const float bA = ba[tid & 31];
    const float bB = bb[tid & 31];

    // ---- stage S block (NP x 32, contiguous) into sSup (stride 33) ----
    const float* Sg = S + (size_t)base * 32;
    constexpr int PIECES = NP * 8;
    constexpr int PSL = (PIECES + 255) / 256;
#pragma unroll
    for (int q = 0; q < PSL; ++q) {
        const int i = tid + q * 256;
        if (i < PIECES) {
            const float4 v = *(const float4*)(Sg + (size_t)i * 4);
            *(float4*)&sSup[(i >> 3) * ST + (i & 7) * 4] = v;
        }
    }
    __syncthreads();

    // ---- agg1 + relu -> sH ----
    agg_phase<ST>(base, NP, cols, vals, sSup, bA, sH, tid);
    __syncthreads();

    // ---- L2 GEMM: support2 = h1 @ Wb -> sSup ----
    if (tid < NP) {
        float acc2[32];
#pragma unroll
        for (int c = 0; c < 32; ++c) acc2[c] = 0.f;
        const float* xrow = &sH[tid * ST];
#pragma unroll 1
        for (int k4 = 0; k4 < 32; k4 += 4) {
            const float4 x4 = *(const float4*)&xrow[k4];
#pragma unroll
            for (int kk = 0; kk < 4; ++kk) {
                const float xs = (&x4.x)[kk];
                const float* w = Wb + (k4 + kk) * 32;
#pragma unroll
                for (int c4 = 0; c4 < 8; ++c4) {
                    const float4 wv = *(const float4*)&w[c4 * 4];
                    acc2[c4 * 4 + 0] += xs * wv.x;
                    acc2[c4 * 4 + 1] += xs * wv.y;
                    acc2[c4 * 4 + 2] += xs * wv.z;
                    acc2[c4 * 4 + 3] += xs * wv.w;
                }
            }
        }
#pragma unroll
        for (int c4 = 0; c4 < 8; ++c4) {
            float4 o;
            o.x = acc2[c4 * 4 + 0]; o.y = acc2[c4 * 4 + 1];
            o.z = acc2[c4 * 4 + 2]; o.w = acc2[c4 * 4 + 3];
            *(float4*)&sSup[tid * ST + c4 * 4] = o;
        }
    }
    __syncthreads();

    // ---- agg2 + relu -> sH ----
    agg_phase<ST>(base, NP, cols, vals, sSup, bB, sH, tid);
    __syncthreads();

    // ---- pool mean+max over nodes ----
    const int h = tid & 31, sl = tid >> 5;
    float sum = 0.f, mx = -1e30f;
    for (int n = sl; n < NP; n += 8) {
        const float v = sH[n * ST + h];
        sum += v;
        mx = fmaxf(mx, v);
    }
    float* sS = sSup;          // support2 dead
    float* sM = sSup + 256;
    sS[tid] = sum;
    sM[tid] = mx;
    __syncthreads();
    if (tid < 32) {
#pragma unroll
        for (int q = 1; q < 8; ++q) {
            sum += sS[tid + 32 * q];
            mx = fmaxf(mx, sM[tid + 32 * q]);
        }
        feats[(size_t)g * 128 + foff + tid] = sum * (1.0f / NP);
        feats[(size_t)g * 128 + foff + 32 + tid] = mx;
    }
}

__global__ __launch_bounds__(256, 3) void graph_fused(
        const float* __restrict__ S1, const int* __restrict__ cols1,
        const float* __restrict__ vals1, const float* __restrict__ b1a,
        const float* __restrict__ W1b, const float* __restrict__ b1b,
        const float* __restrict__ S2, const int* __restrict__ cols2,
        const float* __restrict__ vals2, const float* __restrict__ b2a,
        const float* __restrict__ W2b, const float* __restrict__ b2b,
        float* __restrict__ feats) {
    __shared__ float sSup[N2P * 33];   // 26.4 KB
    __shared__ float sH[N2P * 33];     // 26.4 KB
    const int bid = blockIdx.x;
    const int g = bid >> 1;            // interleave branches: tail balance
    if ((bid & 1) == 0)
        graph_phase<N1P>(g, S1, cols1, vals1, b1a, W1b, b1b, feats, 0, sSup, sH);
    else
        graph_phase<N2P>(g, S2, cols2, vals2, b2a, W2b, b2b, feats, 64, sSup, sH);
}

// ---------------------------------------------------------------------------
// Fallback: proven R5 monolithic per-graph kernel (used if ws too small)
// ---------------------------------------------------------------------------
template <int NP>
__device__ void branch_graph(int g,
                             const float* __restrict__ X,
                             const int* __restrict__ cols,
                             const float* __restrict__ vals,
                             const float* __restrict__ Wa,
                             const float* __restrict__ ba,
                             const float* __restrict__ Wb,
                             const float* __restrict__ bb,
                             float* __restrict__ feats, int foff,
                             float* sSup, float* sH) {
    constexpr int ST = 33;
    constexpr int KC = 16;
    constexpr int SXS = 20;
    constexpr int NSLOT = NP * 4;
    constexpr int PSL = (NSLOT + 255) / 256;

    const int tid = threadIdx.x;
    const int base = g * NP;
    const float* xg = X + (size_t)base * NP;
    const float bA = ba[tid & 31];
    const float bB = bb[tid & 31];

    float* sX = sSup;

    float acc[32];
#pragma unroll
    for (int c = 0; c < 32; ++c) acc[c] = 0.f;

    const int NC = (NP + KC - 1) / KC;

    float4 cur[PSL], nxt[PSL];

    auto load_chunk = [&](int kc, float4* buf) {
        const int k0 = kc * KC;
        const int kw = (NP - k0) < KC ? (NP - k0) : KC;
        const int pieces = kw >> 2;
#pragma unroll
        for (int q = 0; q < PSL; ++q) {
            const int i = tid + q * 256;
            float4 v = make_float4(0.f, 0.f, 0.f, 0.f);
            if (i < NSLOT) {
                const int row = i >> 2, p = i & 3;
                if (p < pieces)
                    v = *(const float4*)(xg + (size_t)row * NP + k0 + p * 4);
            }
            buf[q] = v;
        }
    };
    auto store_chunk = [&](const float4* buf) {
#pragma unroll
        for (int q = 0; q < PSL; ++q) {
            const int i = tid + q * 256;
            if (i < NSLOT) {
                const int row = i >> 2, p = i & 3;
                *(float4*)&sX[row * SXS + p * 4] = buf[q];
            }
        }
    };

    load_chunk(0, cur);
#pragma unroll 1
    for (int kc = 0; kc < NC; ++kc) {
        __syncthreads();
        store_chunk(cur);
        __syncthreads();
        if (kc + 1 < NC) load_chunk(kc + 1, nxt);
        const int k0 = kc * KC;
        const int kw = (NP - k0) < KC ? (NP - k0) : KC;
        if (tid < NP) {
            const float* xrow = &sX[tid * SXS];
            const float* wb0 = Wa + (size_t)k0 * 32;
#pragma unroll 1
            for (int k4 = 0; k4 < kw; k4 += 4) {
                const float4 x4 = *(const float4*)&xrow[k4];
#pragma unroll
                for (int kk = 0; kk < 4; ++kk) {
                    const float xs = (&x4.x)[kk];
                    const float* w = wb0 + (k4 + kk) * 32;
#pragma unroll
                    for (int c4 = 0; c4 < 8; ++c4) {
                        const float4 wv = *(const float4*)&w[c4 * 4];
                        acc[c4 * 4 + 0] += xs * wv.x;
                        acc[c4 * 4 + 1] += xs * wv.y;
                        acc[c4 * 4 + 2] += xs * wv.z;
                        acc[c4 * 4 + 3] += xs * wv.w;
                    }
                }
            }
        }
#pragma unroll
        for (int q = 0; q < PSL; ++q) cur[q] = nxt[q];
    }
    __syncthreads();

    if (tid < NP) {
#pragma unroll
        for (int c4 = 0; c4 < 8; ++c4) {
            float4 o;
            o.x = acc[c4 * 4 + 0]; o.y = acc[c4 * 4 + 1];
            o.z = acc[c4 * 4 + 2]; o.w = acc[c4 * 4 + 3];
            *(float4*)&sSup[tid * ST + c4 * 4] = o;
        }
    }
    __syncthreads();

    agg_phase<ST>(base, NP, cols, vals, sSup, bA, sH, tid);
    __syncthreads();

    if (tid < NP) {
        float acc2[32];
#pragma unroll
        for (int c = 0; c < 32; ++c) acc2[c] = 0.f;
        const float* xrow = &sH[tid * ST];
#pragma unroll 1
        for (int k4 = 0; k4 < 32; k4 += 4) {
            const float4 x4 = *(const float4*)&xrow[k4];
#pragma unroll
            for (int kk = 0; kk < 4; ++kk) {
                const float xs = (&x4.x)[kk];
                const float* w = Wb + (k4 + kk) * 32;
#pragma unroll
                for (int c4 = 0; c4 < 8; ++c4) {
                    const float4 wv = *(const float4*)&w[c4 * 4];
                    acc2[c4 * 4 + 0] += xs * wv.x;
                    acc2[c4 * 4 + 1] += xs * wv.y;
                    acc2[c4 * 4 + 2] += xs * wv.z;
                    acc2[c4 * 4 + 3] += xs * wv.w;
                }
            }
        }
#pragma unroll
        for (int c4 = 0; c4 < 8; ++c4) {
            float4 o;
            o.x = acc2[c4 * 4 + 0]; o.y = acc2[c4 * 4 + 1];
            o.z = acc2[c4 * 4 + 2]; o.w = acc2[c4 * 4 + 3];
            *(float4*)&sSup[tid * ST + c4 * 4] = o;
        }
    }
    __syncthreads();

    agg_phase<ST>(base, NP, cols, vals, sSup, bB, sH, tid);
    __syncthreads();

    const int h = tid & 31, sl = tid >> 5;
    float sum = 0.f, mx = -1e30f;
    for (int n = sl; n < NP; n += 8) {
        const float v = sH[n * ST + h];
        sum += v;
        mx = fmaxf(mx, v);
    }
    float* sS = sSup;
    float* sM = sSup + 256;
    sS[tid] = sum;
    sM[tid] = mx;
    __syncthreads();
    if (tid < 32) {
#pragma unroll
        for (int q = 1; q < 8; ++q) {
            sum += sS[tid + 32 * q];
            mx = fmaxf(mx, sM[tid + 32 * q]);
        }
        feats[(size_t)g * 128 + foff + tid] = sum * (1.0f / NP);
        feats[(size_t)g * 128 + foff + 32 + tid] = mx;
    }
}

__global__ __launch_bounds__(256, 3) void fused_branches(
        const float* __restrict__ x1, const int* __restrict__ cols1,
        const float* __restrict__ vals1,
        const float* __restrict__ W1a, const float* __restrict__ b1a,
        const float* __restrict__ W1b, const float* __restrict__ b1b,
        const float* __restrict__ x2, const int* __restrict__ cols2,
        const float* __restrict__ vals2,
        const float* __restrict__ W2a, const float* __restrict__ b2a,
        const float* __restrict__ W2b, const float* __restrict__ b2b,
        float* __restrict__ feats) {
    __shared__ float sSup[N2P * 33];
    __shared__ float sH[N2P * 33];
    const int bid = blockIdx.x;
    if (bid < NB) {
        branch_graph<N1P>(bid, x1, cols1, vals1, W1a, b1a, W1b, b1b, feats, 0,
                          sSup, sH);
    } else {
        branch_graph<N2P>(bid - NB, x2, cols2, vals2, W2a, b2a, W2b, b2b, feats,
                          64, sSup, sH);
    }
}

// ---------------------------------------------------------------------------
// MLP head: [B,128] -> relu(fc1) -> relu(fc2) -> fc3 -> [B,2]
// ---------------------------------------------------------------------------
__global__ __launch_bounds__(256) void mlp_head(const float* __restrict__ feats,
                                                const float* __restrict__ W1,
                                                const float* __restrict__ b1,
                                                const float* __restrict__ W2,
                                                const float* __restrict__ b2,
                                                const float* __restrict__ W3,
                                                const float* __restrict__ b3,
                                                float* __restrict__ out) {
    __shared__ float sW1[128 * 32];
    __shared__ float sW2[32 * 16];
    __shared__ float sW3[16 * 2];
    __shared__ float sB1[32], sB2[16], sB3[2];
    __shared__ float sF[8 * 128];
    __shared__ float sH1[8 * 32];
    __shared__ float sH2[8 * 16];

    const int tid = threadIdx.x;
    for (int idx = tid; idx < 128 * 32; idx += 256) sW1[idx] = W1[idx];
    for (int idx = tid; idx < 32 * 16; idx += 256) sW2[idx] = W2[idx];
    if (tid < 32) { sW3[tid] = W3[tid]; sB1[tid] = b1[tid]; }
    if (tid < 16) sB2[tid] = b2[tid];
    if (tid < 2) sB3[tid] = b3[tid];
    const long g0 = (long)blockIdx.x * 8;
    for (int idx = tid; idx < 1024; idx += 256) sF[idx] = feats[g0 * 128 + idx];
    __syncthreads();

    const int g = tid >> 5, h = tid & 31;
    float a1 = sB1[h];
#pragma unroll 4
    for (int k = 0; k < 128; ++k) a1 += sF[g * 128 + k] * sW1[k * 32 + h];
    sH1[g * 32 + h] = fmaxf(a1, 0.f);
    __syncthreads();

    if (h < 16) {
        float a2 = sB2[h];
#pragma unroll
        for (int k = 0; k < 32; ++k) a2 += sH1[g * 32 + k] * sW2[k * 16 + h];
        sH2[g * 16 + h] = fmaxf(a2, 0.f);
    }
    __syncthreads();

    if (h < 2) {
        float a3 = sB3[h];
#pragma unroll
        for (int k = 0; k < 16; ++k) a3 += sH2[g * 16 + k] * sW3[k * 2 + h];
        out[(g0 + g) * 2 + h] = a3;
    }
}

// ---------------------------------------------------------------------------
extern "C" void kernel_launch(void* const* d_in, const int* in_sizes, int n_in,
                              void* d_out, int out_size, void* d_ws, size_t ws_size,
                              hipStream_t stream) {
    const int*   cols1 = (const int*)d_in[1];
    const float* vals1 = (const float*)d_in[2];
    const float* x1    = (const float*)d_in[3];
    const int*   cols2 = (const int*)d_in[5];
    const float* vals2 = (const float*)d_in[6];
    const float* x2    = (const float*)d_in[7];
    const float* W1a = (const float*)d_in[8];
    const float* b1a = (const float*)d_in[9];
    const float* W1b = (const float*)d_in[10];
    const float* b1b = (const float*)d_in[11];
    const float* W2a = (const float*)d_in[12];
    const float* b2a = (const float*)d_in[13];
    const float* W2b = (const float*)d_in[14];
    const float* b2b = (const float*)d_in[15];
    const float* fc1_W = (const float*)d_in[16];
    const float* fc1_b = (const float*)d_in[17];
    const float* fc2_W = (const float*)d_in[18];
    const float* fc2_b = (const float*)d_in[19];
    const float* fc3_W = (const float*)d_in[20];
    const float* fc3_b = (const float*)d_in[21];
    float* out = (float*)d_out;

    float* feats = (float*)d_ws;                       // NB*128 floats
    const size_t FEATS_N = (size_t)NB * 128;
    const size_t S1_N = (size_t)NB * N1P * 32;         // 3.80M floats
    const size_t S2_N = (size_t)NB * N2P * 32;         // 6.55M floats
    const size_t need = (FEATS_N + S1_N + S2_N) * sizeof(float);  // ~42 MB

    if (ws_size >= need) {
        float* S1 = feats + FEATS_N;
        float* S2 = S1 + S1_N;
        gemm1_kernel<<<T1 + T2, 256, 0, stream>>>(x1, W1a, S1, x2, W2a, S2);
        graph_fused<<<2 * NB, 256, 0, stream>>>(
            S1, cols1, vals1, b1a, W1b, b1b,
            S2, cols2, vals2, b2a, W2b, b2b, feats);
    } else {
        fused_branches<<<2 * NB, 256, 0, stream>>>(
            x1, cols1, vals1, W1a, b1a, W1b, b1b,
            x2, cols2, vals2, W2a, b2a, W2b, b2b, feats);
    }

    mlp_head<<<NB / 8, 256, 0, stream>>>(feats, fc1_W, fc1_b, fc2_W, fc2_b,
                                         fc3_W, fc3_b, out);
}